// Round 1
// baseline (1006.718 us; speedup 1.0000x reference)
//
#include <hip/hip_runtime.h>
#include <hip/hip_bf16.h>

#define T_TOK 2048
#define HID 2048
#define MINTER 1024
#define SINTER 4096
#define NEXP 16

typedef unsigned short u16;
typedef unsigned int u32;
typedef short short8 __attribute__((ext_vector_type(8)));
typedef float f32x4 __attribute__((ext_vector_type(4)));

__device__ __forceinline__ u16 f2bf(float f) {
    union { float f; unsigned u; } v; v.f = f;
    unsigned u = v.u;
    unsigned r = (u + 0x7FFFu + ((u >> 16) & 1u)) >> 16;
    return (u16)r;
}

// async global->LDS, 16B per lane; LDS dest must be wave-uniform base (+lane*16)
__device__ __forceinline__ void gload16(const void* g, void* s) {
    __builtin_amdgcn_global_load_lds(
        (const __attribute__((address_space(1))) u32*)g,
        (__attribute__((address_space(3))) u32*)s, 16, 0, 0);
}

// ---------------- x fp32 -> bf16 ----------------
__global__ __launch_bounds__(256) void cvt_kernel(const float* __restrict__ in,
                                                  u16* __restrict__ out, int n4) {
    int i = blockIdx.x * 256 + threadIdx.x;
    if (i >= n4) return;
    float4 v = ((const float4*)in)[i];
    ushort4 o;
    o.x = f2bf(v.x); o.y = f2bf(v.y); o.z = f2bf(v.z); o.w = f2bf(v.w);
    ((ushort4*)out)[i] = o;
}

// ---------------- [Z][K][N] fp32 -> [Z][N][K] bf16 transpose ----------------
__global__ __launch_bounds__(256) void transpose_cvt_kernel(
    const float* __restrict__ in, u16* __restrict__ out, int K, int N)
{
    __shared__ float t[64][65];
    size_t zoff = (size_t)blockIdx.z * K * N;
    in += zoff; out += zoff;
    int k0 = blockIdx.x * 64, n0 = blockIdx.y * 64;
    int tid = threadIdx.x;
    int r = tid >> 4, c4 = (tid & 15) * 4;
    #pragma unroll
    for (int i = 0; i < 4; i++) {
        float4 v = *(const float4*)&in[(size_t)(k0 + r + 16*i) * N + n0 + c4];
        t[r + 16*i][c4]     = v.x;
        t[r + 16*i][c4 + 1] = v.y;
        t[r + 16*i][c4 + 2] = v.z;
        t[r + 16*i][c4 + 3] = v.w;
    }
    __syncthreads();
    #pragma unroll
    for (int i = 0; i < 4; i++) {
        int n = r + 16*i;
        ushort4 o;
        o.x = f2bf(t[c4 + 0][n]);
        o.y = f2bf(t[c4 + 1][n]);
        o.z = f2bf(t[c4 + 2][n]);
        o.w = f2bf(t[c4 + 3][n]);
        *(ushort4*)&out[(size_t)(n0 + n) * K + k0 + c4] = o;
    }
}

// ---------------- router: logits -> sigmoid -> group top-k -> scatter ----------------
__global__ __launch_bounds__(256) void router_kernel(
    const float* __restrict__ x, const float* __restrict__ rw, const float* __restrict__ ebias,
    int* __restrict__ counts, int* __restrict__ bid, float* __restrict__ bw)
{
    int t = blockIdx.x;
    int tid = threadIdx.x;
    int e = tid >> 4, j = tid & 15;
    const float* xp = x + (size_t)t * HID;
    const float* wp = rw + (size_t)e * HID;
    float sum = 0.f;
    #pragma unroll 4
    for (int h = j; h < HID; h += 16) sum += xp[h] * wp[h];
    sum += __shfl_xor(sum, 8);
    sum += __shfl_xor(sum, 4);
    sum += __shfl_xor(sum, 2);
    sum += __shfl_xor(sum, 1);
    __shared__ float sc[NEXP];
    if (j == 0) sc[e] = 1.f / (1.f + expf(-sum));
    __syncthreads();
    if (tid == 0) {
        float s[NEXP];
        #pragma unroll
        for (int i = 0; i < NEXP; i++) s[i] = sc[i] + ebias[i];
        float gs[4];
        #pragma unroll
        for (int g = 0; g < 4; g++) {
            float a = s[4*g], b = s[4*g+1], c = s[4*g+2], d = s[4*g+3];
            float hi1 = fmaxf(a,b), lo1 = fminf(a,b);
            float hi2 = fmaxf(c,d), lo2 = fminf(c,d);
            float mx = fmaxf(hi1, hi2);
            float se = fmaxf(fminf(hi1, hi2), fmaxf(lo1, lo2));
            gs[g] = mx + se;
        }
        int g0 = 0;
        for (int g = 1; g < 4; g++) if (gs[g] > gs[g0]) g0 = g;
        int g1 = -1;
        for (int g = 0; g < 4; g++) { if (g == g0) continue; if (g1 < 0 || gs[g] > gs[g1]) g1 = g; }
        int e0 = -1, e1 = -1;
        for (int i = 0; i < NEXP; i++) {
            int g = i >> 2;
            if (g != g0 && g != g1) continue;
            if (e0 < 0 || s[i] > s[e0]) e0 = i;
        }
        for (int i = 0; i < NEXP; i++) {
            int g = i >> 2;
            if (g != g0 && g != g1) continue;
            if (i == e0) continue;
            if (e1 < 0 || s[i] > s[e1]) e1 = i;
        }
        float w0 = sc[e0], w1 = sc[e1];
        float inv = 1.f / (w0 + w1 + 1e-20f);
        w0 *= inv; w1 *= inv;
        int p0 = atomicAdd(&counts[e0], 1);
        bid[e0 * T_TOK + p0] = t * 2;
        bw [e0 * T_TOK + p0] = w0;
        int p1 = atomicAdd(&counts[e1], 1);
        bid[e1 * T_TOK + p1] = t * 2 + 1;
        bw [e1 * T_TOK + p1] = w1;
    }
}

// =================== fused UP dispatch ===================
// blocks [0,512):   shared-up  : hsh[T,S]   = relu2(xbf @ suT^T)       (bf16)
// blocks [512,...): routed-up  : act[tk,I]  = relu2(xbf[t] @ wuT^T)*w  (bf16)
// Both K = HID. 2-phase double-buffered pipeline (T3-minimum):
//   STAGE(next) -> compute(cur) -> vmcnt(0)+s_barrier  (one barrier per K-step)
__global__ __launch_bounds__(256, 2) void up_kernel(
    const u16* __restrict__ xbf, const u16* __restrict__ suT,
    const u16* __restrict__ wuT, u16* __restrict__ hsh, u16* __restrict__ act,
    const int* __restrict__ counts, const int* __restrict__ bid,
    const float* __restrict__ bw)
{
    __shared__ alignas(16) u16 As[2][128 * 64];
    __shared__ alignas(16) u16 Bs[2][128 * 64];
    __shared__ int   idsL[128];
    __shared__ float wL[128];

    int b = blockIdx.x;
    int tid = threadIdx.x;
    bool routed = (b >= 512);
    int e = 0, mblk, nblk, M = T_TOK;
    const u16* BT;
    if (!routed) {
        // XCD-aware bijective swizzle (512 % 8 == 0): XCD x gets a contiguous
        // chunk of 64 tiles -> 4 B-panels (2 MB) resident in its private L2.
        int swz = (b & 7) * 64 + (b >> 3);
        mblk = swz & 15; nblk = swz >> 4; BT = suT;
    }
    else {
        int rb = b - 512; e = rb >> 7; int rem = rb & 127;
        mblk = rem & 15; nblk = rem >> 4;
        M = counts[e];
        if (mblk * 128 >= M) return;
        BT = wuT + (size_t)e * MINTER * HID;
    }
    int m0 = mblk * 128, n0 = nblk * 128;

    if (routed) {
        if (tid < 128) {
            int p = m0 + tid; if (p >= M) p = M - 1;
            idsL[tid] = bid[e * T_TOK + p];
            wL[tid]   = bw [e * T_TOK + p];
        }
        __syncthreads();
    }

    int lane = tid & 63, wid = tid >> 6;
    int rsub = lane >> 3, kseg = (lane & 7) * 8;

    const u16* aG[4]; const u16* bG[4];
    #pragma unroll
    for (int i = 0; i < 4; i++) {
        int rr = wid * 32 + i * 8 + rsub;
        size_t ar = routed ? (size_t)(idsL[rr] >> 1) : (size_t)(m0 + rr);
        aG[i] = xbf + ar * HID + kseg;
        bG[i] = BT + (size_t)(n0 + rr) * HID + kseg;
    }

    f32x4 acc[4][4] = {};
    int wm = (wid & 1) * 64, wn = (wid >> 1) * 64;
    int lrow = lane & 15, lq = lane >> 4;

    auto STAGE = [&](int buf, int k0) {
        #pragma unroll
        for (int i = 0; i < 4; i++) {
            gload16(aG[i] + k0, &As[buf][(wid * 32 + i * 8) * 64]);
            gload16(bG[i] + k0, &Bs[buf][(wid * 32 + i * 8) * 64]);
        }
    };
    auto COMPUTE = [&](int buf) {
        #pragma unroll
        for (int kc = 0; kc < 64; kc += 32) {
            short8 af[4], bf2[4];
            #pragma unroll
            for (int im = 0; im < 4; im++)
                af[im] = *(const short8*)&As[buf][(wm + im*16 + lrow) * 64 + kc + lq * 8];
            #pragma unroll
            for (int in = 0; in < 4; in++)
                bf2[in] = *(const short8*)&Bs[buf][(wn + in*16 + lrow) * 64 + kc + lq * 8];
            __builtin_amdgcn_s_setprio(1);
            #pragma unroll
            for (int im = 0; im < 4; im++)
                #pragma unroll
                for (int in = 0; in < 4; in++)
                    acc[im][in] = __builtin_amdgcn_mfma_f32_16x16x32_bf16(
                        af[im], bf2[in], acc[im][in], 0, 0, 0);
            __builtin_amdgcn_s_setprio(0);
        }
    };
    auto SYNC = [&]() {
        asm volatile("s_waitcnt vmcnt(0)" ::: "memory");
        __builtin_amdgcn_s_barrier();
        __builtin_amdgcn_sched_barrier(0);
    };

    const int NT = HID / 64;  // 32, even
    STAGE(0, 0);
    SYNC();
    #pragma unroll 1
    for (int t = 0; t < NT; t += 2) {
        if (t + 1 < NT) STAGE(1, (t + 1) * 64);
        COMPUTE(0);
        SYNC();
        if (t + 2 < NT) STAGE(0, (t + 2) * 64);
        COMPUTE(1);
        SYNC();
    }

    #pragma unroll
    for (int im = 0; im < 4; im++) {
        #pragma unroll
        for (int in = 0; in < 4; in++) {
            int ncol = n0 + wn + in*16 + lrow;
            #pragma unroll
            for (int r = 0; r < 4; r++) {
                int mrow = wm + im*16 + lq*4 + r;
                float v = acc[im][in][r];
                float rl = v > 0.f ? v * v : 0.f;
                if (!routed) {
                    hsh[(size_t)(m0 + mrow) * SINTER + ncol] = f2bf(rl);
                } else {
                    if (m0 + mrow < M) {
                        int tk = idsL[mrow];
                        act[(size_t)tk * MINTER + ncol] = f2bf(rl * wL[mrow]);
                    }
                }
            }
        }
    }
}

// =================== fused DOWN dispatch ===================
// blocks [0,256):   shared-down: sh_out[T,H] = hsh @ sdT^T   (fp32), K=S
// blocks [256,...): routed-down: r_out[tk,H] = act[tk] @ wdT^T (fp32), K=I
__global__ __launch_bounds__(256, 2) void down_kernel(
    const u16* __restrict__ hsh, const u16* __restrict__ sdT,
    const u16* __restrict__ act, const u16* __restrict__ wdT,
    float* __restrict__ sh_out, float* __restrict__ r_out,
    const int* __restrict__ counts, const int* __restrict__ bid)
{
    __shared__ alignas(16) u16 As[2][128 * 64];
    __shared__ alignas(16) u16 Bs[2][128 * 64];
    __shared__ int idsL[128];

    int b = blockIdx.x;
    int tid = threadIdx.x;
    bool routed = (b >= 256);
    int e = 0, mblk, nblk, M = T_TOK, K, ldA;
    const u16* A; const u16* BT; float* C;
    if (!routed) {
        // XCD-aware bijective swizzle (256 % 8 == 0): 32 tiles / XCD chunk.
        int swz = (b & 7) * 32 + (b >> 3);
        mblk = swz & 15; nblk = swz >> 4;
        A = hsh; ldA = SINTER; K = SINTER; BT = sdT; C = sh_out;
    } else {
        int rb = b - 256; e = rb >> 8; int rem = rb & 255;
        mblk = rem & 15; nblk = rem >> 4;
        M = counts[e];
        if (mblk * 128 >= M) return;
        A = act; ldA = MINTER; K = MINTER;
        BT = wdT + (size_t)e * HID * MINTER;
        C = r_out;
    }
    int m0 = mblk * 128, n0 = nblk * 128;

    if (routed) {
        if (tid < 128) {
            int p = m0 + tid; if (p >= M) p = M - 1;
            idsL[tid] = bid[e * T_TOK + p];
        }
        __syncthreads();
    }

    int lane = tid & 63, wid = tid >> 6;
    int rsub = lane >> 3, kseg = (lane & 7) * 8;

    const u16* aG[4]; const u16* bG[4];
    #pragma unroll
    for (int i = 0; i < 4; i++) {
        int rr = wid * 32 + i * 8 + rsub;
        size_t ar = routed ? (size_t)idsL[rr] : (size_t)(m0 + rr);
        aG[i] = A + ar * (size_t)ldA + kseg;
        bG[i] = BT + (size_t)(n0 + rr) * K + kseg;
    }

    f32x4 acc[4][4] = {};
    int wm = (wid & 1) * 64, wn = (wid >> 1) * 64;
    int lrow = lane & 15, lq = lane >> 4;

    auto STAGE = [&](int buf, int k0) {
        #pragma unroll
        for (int i = 0; i < 4; i++) {
            gload16(aG[i] + k0, &As[buf][(wid * 32 + i * 8) * 64]);
            gload16(bG[i] + k0, &Bs[buf][(wid * 32 + i * 8) * 64]);
        }
    };
    auto COMPUTE = [&](int buf) {
        #pragma unroll
        for (int kc = 0; kc < 64; kc += 32) {
            short8 af[4], bf2[4];
            #pragma unroll
            for (int im = 0; im < 4; im++)
                af[im] = *(const short8*)&As[buf][(wm + im*16 + lrow) * 64 + kc + lq * 8];
            #pragma unroll
            for (int in = 0; in < 4; in++)
                bf2[in] = *(const short8*)&Bs[buf][(wn + in*16 + lrow) * 64 + kc + lq * 8];
            __builtin_amdgcn_s_setprio(1);
            #pragma unroll
            for (int im = 0; im < 4; im++)
                #pragma unroll
                for (int in = 0; in < 4; in++)
                    acc[im][in] = __builtin_amdgcn_mfma_f32_16x16x32_bf16(
                        af[im], bf2[in], acc[im][in], 0, 0, 0);
            __builtin_amdgcn_s_setprio(0);
        }
    };
    auto SYNC = [&]() {
        asm volatile("s_waitcnt vmcnt(0)" ::: "memory");
        __builtin_amdgcn_s_barrier();
        __builtin_amdgcn_sched_barrier(0);
    };

    const int NT = K / 64;  // 64 (shared) or 16 (routed), always even
    STAGE(0, 0);
    SYNC();
    #pragma unroll 1
    for (int t = 0; t < NT; t += 2) {
        if (t + 1 < NT) STAGE(1, (t + 1) * 64);
        COMPUTE(0);
        SYNC();
        if (t + 2 < NT) STAGE(0, (t + 2) * 64);
        COMPUTE(1);
        SYNC();
    }

    #pragma unroll
    for (int im = 0; im < 4; im++) {
        #pragma unroll
        for (int in = 0; in < 4; in++) {
            int ncol = n0 + wn + in*16 + lrow;
            #pragma unroll
            for (int r = 0; r < 4; r++) {
                int mrow = wm + im*16 + lq*4 + r;
                float v = acc[im][in][r];
                if (!routed) {
                    C[(size_t)(m0 + mrow) * HID + ncol] = v;
                } else {
                    if (m0 + mrow < M) {
                        int tk = idsL[mrow];
                        C[(size_t)tk * HID + ncol] = v;
                    }
                }
            }
        }
    }
}

// ---------------- out = shared + routed[2t] + routed[2t+1] ----------------
__global__ __launch_bounds__(256) void final_add_kernel(
    const float* __restrict__ sh, const float* __restrict__ ro,
    float* __restrict__ out, int n4)
{
    int i = blockIdx.x * 256 + threadIdx.x;
    if (i >= n4) return;
    int t  = i >> 9;
    int c4 = i & 511;
    float4 a = ((const float4*)sh)[i];
    float4 b = ((const float4*)ro)[(size_t)(2*t)     * 512 + c4];
    float4 c = ((const float4*)ro)[(size_t)(2*t + 1) * 512 + c4];
    float4 o;
    o.x = a.x + b.x + c.x;
    o.y = a.y + b.y + c.y;
    o.z = a.z + b.z + c.z;
    o.w = a.w + b.w + c.w;
    ((float4*)out)[i] = o;
}

extern "C" void kernel_launch(void* const* d_in, const int* in_sizes, int n_in,
                              void* d_out, int out_size, void* d_ws, size_t ws_size,
                              hipStream_t stream) {
    (void)in_sizes; (void)n_in; (void)out_size; (void)ws_size;
    const float* x  = (const float*)d_in[0];
    const float* rw = (const float*)d_in[1];
    const float* eb = (const float*)d_in[2];
    const float* wu = (const float*)d_in[3];
    const float* wd = (const float*)d_in[4];
    const float* su = (const float*)d_in[5];
    const float* sd = (const float*)d_in[6];
    float* out = (float*)d_out;

    char* p = (char*)d_ws;
    u16*  x_bf = (u16*)p;  p += (size_t)T_TOK * HID * 2;            // 8.4 MB
    u16*  suT  = (u16*)p;  p += (size_t)SINTER * HID * 2;           // 16.8 MB
    u16*  sdT  = (u16*)p;  p += (size_t)HID * SINTER * 2;           // 16.8 MB
    u16*  wuT  = (u16*)p;  p += (size_t)NEXP * MINTER * HID * 2;    // 67.1 MB
    u16*  wdT  = (u16*)p;  p += (size_t)NEXP * HID * MINTER * 2;    // 67.1 MB
    u16*  hsh  = (u16*)p;  p += (size_t)T_TOK * SINTER * 2;         // 16.8 MB
    u16*  act  = (u16*)p;  p += (size_t)T_TOK * 2 * MINTER * 2;     // 8.4 MB
    int*   counts = (int*)p; p += 256;
    int*   bid    = (int*)p; p += (size_t)NEXP * T_TOK * 4;
    float* bw     = (float*)p; p += (size_t)NEXP * T_TOK * 4;
    // aliased (lifetimes disjoint, stream-ordered):
    float* sh_out = (float*)x_bf;   // 16.8 MB over x_bf+suT (dead after up)
    float* r_out  = (float*)wuT;    // 33.6 MB over wuT (dead after up)

    hipMemsetAsync(counts, 0, NEXP * sizeof(int), stream);

    int n4 = T_TOK * HID / 4;
    cvt_kernel<<<(n4 + 255) / 256, 256, 0, stream>>>(x, x_bf, n4);

    // weight convert+transpose to bf16 B^T layouts
    transpose_cvt_kernel<<<dim3(2048/64, 4096/64, 1),  256, 0, stream>>>(su, suT, 2048, 4096);
    transpose_cvt_kernel<<<dim3(4096/64, 2048/64, 1),  256, 0, stream>>>(sd, sdT, 4096, 2048);
    transpose_cvt_kernel<<<dim3(2048/64, 1024/64, 16), 256, 0, stream>>>(wu, wuT, 2048, 1024);
    transpose_cvt_kernel<<<dim3(1024/64, 2048/64, 16), 256, 0, stream>>>(wd, wdT, 1024, 2048);

    router_kernel<<<T_TOK, 256, 0, stream>>>(x, rw, eb, counts, bid, bw);

    // fused up: 512 shared tiles + 16e*8n*16m routed tiles
    up_kernel<<<512 + NEXP * 8 * 16, 256, 0, stream>>>(
        x_bf, suT, wuT, hsh, act, counts, bid, bw);

    // fused down: 256 shared tiles + 16e*16n*16m routed tiles
    down_kernel<<<256 + NEXP * 16 * 16, 256, 0, stream>>>(
        hsh, sdT, act, wdT, sh_out, r_out, counts, bid);

    final_add_kernel<<<(n4 + 255) / 256, 256, 0, stream>>>(sh_out, r_out, out, n4);
}

// Round 2
// 881.177 us; speedup vs baseline: 1.1425x; 1.1425x over previous
//
#include <hip/hip_runtime.h>
#include <hip/hip_bf16.h>

#define T_TOK 2048
#define HID 2048
#define MINTER 1024
#define SINTER 4096
#define NEXP 16

typedef unsigned short u16;
typedef unsigned int u32;
typedef short short8 __attribute__((ext_vector_type(8)));
typedef float f32x4 __attribute__((ext_vector_type(4)));

__device__ __forceinline__ u16 f2bf(float f) {
    union { float f; unsigned u; } v; v.f = f;
    unsigned u = v.u;
    unsigned r = (u + 0x7FFFu + ((u >> 16) & 1u)) >> 16;
    return (u16)r;
}

// async global->LDS, 16B per lane; LDS dest must be wave-uniform base (+lane*16)
__device__ __forceinline__ void gload16(const void* g, void* s) {
    __builtin_amdgcn_global_load_lds(
        (const __attribute__((address_space(1))) u32*)g,
        (__attribute__((address_space(3))) u32*)s, 16, 0, 0);
}

// ================= fused PREP: cvt + 4 transposes + router in ONE launch =================
// All sub-jobs are mutually independent; fusing removes 5 launch ramp/tail serializations
// and fills the GPU (26624 blocks).
#define CVT_BLKS 4096            // (2048*2048/4)/256
#define SU_BLKS  (32 * 64)       // K=2048 N=4096 -> 2048
#define SD_BLKS  (64 * 32)       // K=4096 N=2048 -> 2048
#define WU_BLKS  (32 * 16 * 16)  // K=2048 N=1024 x16 -> 8192
#define WD_BLKS  (16 * 32 * 16)  // K=1024 N=2048 x16 -> 8192
#define RT_BLKS  T_TOK           // 2048
#define PREP_BLKS (CVT_BLKS + SU_BLKS + SD_BLKS + WU_BLKS + WD_BLKS + RT_BLKS)

// [K][N] fp32 -> [N][K] bf16 64x64 tile transpose through LDS
__device__ __forceinline__ void transpose_body(
    const float* __restrict__ in, u16* __restrict__ out,
    int K, int N, int k0, int n0, float (*t)[65])
{
    int tid = threadIdx.x;
    int r = tid >> 4, c4 = (tid & 15) * 4;
    #pragma unroll
    for (int i = 0; i < 4; i++) {
        float4 v = *(const float4*)&in[(size_t)(k0 + r + 16*i) * N + n0 + c4];
        t[r + 16*i][c4]     = v.x;
        t[r + 16*i][c4 + 1] = v.y;
        t[r + 16*i][c4 + 2] = v.z;
        t[r + 16*i][c4 + 3] = v.w;
    }
    __syncthreads();
    #pragma unroll
    for (int i = 0; i < 4; i++) {
        int n = r + 16*i;
        ushort4 o;
        o.x = f2bf(t[c4 + 0][n]);
        o.y = f2bf(t[c4 + 1][n]);
        o.z = f2bf(t[c4 + 2][n]);
        o.w = f2bf(t[c4 + 3][n]);
        *(ushort4*)&out[(size_t)(n0 + n) * K + k0 + c4] = o;
    }
}

__global__ __launch_bounds__(256) void prep_kernel(
    const float* __restrict__ x, const float* __restrict__ su,
    const float* __restrict__ sd, const float* __restrict__ wu,
    const float* __restrict__ wd, const float* __restrict__ rw,
    const float* __restrict__ eb,
    u16* __restrict__ x_bf, u16* __restrict__ suT, u16* __restrict__ sdT,
    u16* __restrict__ wuT, u16* __restrict__ wdT,
    int* __restrict__ counts, int* __restrict__ bid, float* __restrict__ bw)
{
    __shared__ float ts[64][65];   // transpose tile (router reuses first 16 floats)
    int b = blockIdx.x;
    int tid = threadIdx.x;

    // ---- region 1: x fp32 -> bf16 ----
    if (b < CVT_BLKS) {
        int i = b * 256 + tid;     // exact: 4096*256 == n4
        float4 v = ((const float4*)x)[i];
        ushort4 o;
        o.x = f2bf(v.x); o.y = f2bf(v.y); o.z = f2bf(v.z); o.w = f2bf(v.w);
        ((ushort4*)x_bf)[i] = o;
        return;
    }
    b -= CVT_BLKS;

    // ---- region 2: shared_up [2048][4096] -> suT [4096][2048] ----
    if (b < SU_BLKS) {
        transpose_body(su, suT, 2048, 4096, (b & 31) * 64, (b >> 5) * 64, ts);
        return;
    }
    b -= SU_BLKS;

    // ---- region 3: shared_down [4096][2048] -> sdT [2048][4096] ----
    if (b < SD_BLKS) {
        transpose_body(sd, sdT, 4096, 2048, (b & 63) * 64, (b >> 6) * 64, ts);
        return;
    }
    b -= SD_BLKS;

    // ---- region 4: w_up [16][2048][1024] -> wuT [16][1024][2048] ----
    if (b < WU_BLKS) {
        int z = b >> 9, r = b & 511;                 // 512 tiles per expert
        size_t zo = (size_t)z * 2048 * 1024;
        transpose_body(wu + zo, wuT + zo, 2048, 1024, (r & 31) * 64, (r >> 5) * 64, ts);
        return;
    }
    b -= WU_BLKS;

    // ---- region 5: w_down [16][1024][2048] -> wdT [16][2048][1024] ----
    if (b < WD_BLKS) {
        int z = b >> 9, r = b & 511;
        size_t zo = (size_t)z * 1024 * 2048;
        transpose_body(wd + zo, wdT + zo, 1024, 2048, (r & 15) * 64, (r >> 4) * 64, ts);
        return;
    }
    b -= WD_BLKS;

    // ---- region 6: router ----
    {
        int t = b;
        int e = tid >> 4, j = tid & 15;
        const float* xp = x + (size_t)t * HID;
        const float* wp = rw + (size_t)e * HID;
        float sum = 0.f;
        #pragma unroll 4
        for (int h = j; h < HID; h += 16) sum += xp[h] * wp[h];
        sum += __shfl_xor(sum, 8);
        sum += __shfl_xor(sum, 4);
        sum += __shfl_xor(sum, 2);
        sum += __shfl_xor(sum, 1);
        float* sc = &ts[0][0];
        if (j == 0) sc[e] = 1.f / (1.f + expf(-sum));
        __syncthreads();
        if (tid == 0) {
            float s[NEXP];
            #pragma unroll
            for (int i = 0; i < NEXP; i++) s[i] = sc[i] + eb[i];
            float gs[4];
            #pragma unroll
            for (int g = 0; g < 4; g++) {
                float a = s[4*g], bq = s[4*g+1], c = s[4*g+2], d = s[4*g+3];
                float hi1 = fmaxf(a,bq), lo1 = fminf(a,bq);
                float hi2 = fmaxf(c,d), lo2 = fminf(c,d);
                float mx = fmaxf(hi1, hi2);
                float se = fmaxf(fminf(hi1, hi2), fmaxf(lo1, lo2));
                gs[g] = mx + se;
            }
            int g0 = 0;
            for (int g = 1; g < 4; g++) if (gs[g] > gs[g0]) g0 = g;
            int g1 = -1;
            for (int g = 0; g < 4; g++) { if (g == g0) continue; if (g1 < 0 || gs[g] > gs[g1]) g1 = g; }
            int e0 = -1, e1 = -1;
            for (int i = 0; i < NEXP; i++) {
                int g = i >> 2;
                if (g != g0 && g != g1) continue;
                if (e0 < 0 || s[i] > s[e0]) e0 = i;
            }
            for (int i = 0; i < NEXP; i++) {
                int g = i >> 2;
                if (g != g0 && g != g1) continue;
                if (i == e0) continue;
                if (e1 < 0 || s[i] > s[e1]) e1 = i;
            }
            float w0 = sc[e0], w1 = sc[e1];
            float inv = 1.f / (w0 + w1 + 1e-20f);
            w0 *= inv; w1 *= inv;
            int p0 = atomicAdd(&counts[e0], 1);
            bid[e0 * T_TOK + p0] = t * 2;
            bw [e0 * T_TOK + p0] = w0;
            int p1 = atomicAdd(&counts[e1], 1);
            bid[e1 * T_TOK + p1] = t * 2 + 1;
            bw [e1 * T_TOK + p1] = w1;
        }
    }
}

// =================== fused UP dispatch ===================
// blocks [0,512):   shared-up  : hsh[T,S]   = relu2(xbf @ suT^T)       (bf16)
// blocks [512,...): routed-up  : act[tk,I]  = relu2(xbf[t] @ wuT^T)*w  (bf16)
// Round-0 structure (single-buffer, 33KB LDS, 3 blocks/CU) — best measured.
__global__ __launch_bounds__(256, 3) void up_kernel(
    const u16* __restrict__ xbf, const u16* __restrict__ suT,
    const u16* __restrict__ wuT, u16* __restrict__ hsh, u16* __restrict__ act,
    const int* __restrict__ counts, const int* __restrict__ bid,
    const float* __restrict__ bw)
{
    __shared__ alignas(16) u16 As[128 * 64];
    __shared__ alignas(16) u16 Bs[128 * 64];
    __shared__ int   idsL[128];
    __shared__ float wL[128];

    int b = blockIdx.x;
    int tid = threadIdx.x;
    bool routed = (b >= 512);
    int e = 0, mblk, nblk, M = T_TOK;
    const u16* BT;
    if (!routed) {
        // XCD-aware bijective swizzle (512 % 8 == 0): contiguous tile chunk per XCD L2
        int swz = (b & 7) * 64 + (b >> 3);
        mblk = swz & 15; nblk = swz >> 4; BT = suT;
    } else {
        int rb = b - 512; e = rb >> 7; int rem = rb & 127;
        mblk = rem & 15; nblk = rem >> 4;
        M = counts[e];
        if (mblk * 128 >= M) return;
        BT = wuT + (size_t)e * MINTER * HID;
    }
    int m0 = mblk * 128, n0 = nblk * 128;

    if (routed) {
        if (tid < 128) {
            int p = m0 + tid; if (p >= M) p = M - 1;
            idsL[tid] = bid[e * T_TOK + p];
            wL[tid]   = bw [e * T_TOK + p];
        }
        __syncthreads();
    }

    int lane = tid & 63, wid = tid >> 6;
    int rsub = lane >> 3, kseg = (lane & 7) * 8;

    const u16* aG[4]; const u16* bG[4];
    #pragma unroll
    for (int i = 0; i < 4; i++) {
        int rr = wid * 32 + i * 8 + rsub;
        size_t ar = routed ? (size_t)(idsL[rr] >> 1) : (size_t)(m0 + rr);
        aG[i] = xbf + ar * HID + kseg;
        bG[i] = BT + (size_t)(n0 + rr) * HID + kseg;
    }

    f32x4 acc[4][4] = {};
    int wm = (wid & 1) * 64, wn = (wid >> 1) * 64;
    int lrow = lane & 15, lq = lane >> 4;

    for (int k0 = 0; k0 < HID; k0 += 64) {
        #pragma unroll
        for (int i = 0; i < 4; i++) {
            gload16(aG[i] + k0, &As[(wid * 32 + i * 8) * 64]);
            gload16(bG[i] + k0, &Bs[(wid * 32 + i * 8) * 64]);
        }
        __syncthreads();
        #pragma unroll
        for (int kc = 0; kc < 64; kc += 32) {
            short8 af[4], bf2[4];
            #pragma unroll
            for (int im = 0; im < 4; im++)
                af[im] = *(const short8*)&As[(wm + im*16 + lrow) * 64 + kc + lq * 8];
            #pragma unroll
            for (int in = 0; in < 4; in++)
                bf2[in] = *(const short8*)&Bs[(wn + in*16 + lrow) * 64 + kc + lq * 8];
            #pragma unroll
            for (int im = 0; im < 4; im++)
                #pragma unroll
                for (int in = 0; in < 4; in++)
                    acc[im][in] = __builtin_amdgcn_mfma_f32_16x16x32_bf16(
                        af[im], bf2[in], acc[im][in], 0, 0, 0);
        }
        __syncthreads();
    }

    #pragma unroll
    for (int im = 0; im < 4; im++) {
        #pragma unroll
        for (int in = 0; in < 4; in++) {
            int ncol = n0 + wn + in*16 + lrow;
            #pragma unroll
            for (int r = 0; r < 4; r++) {
                int mrow = wm + im*16 + lq*4 + r;
                float v = acc[im][in][r];
                float rl = v > 0.f ? v * v : 0.f;
                if (!routed) {
                    hsh[(size_t)(m0 + mrow) * SINTER + ncol] = f2bf(rl);
                } else {
                    if (m0 + mrow < M) {
                        int tk = idsL[mrow];
                        act[(size_t)tk * MINTER + ncol] = f2bf(rl * wL[mrow]);
                    }
                }
            }
        }
    }
}

// =================== fused DOWN dispatch ===================
// blocks [0,256):   shared-down: sh_out[T,H] = hsh @ sdT^T   (fp32), K=S
// blocks [256,...): routed-down: r_out[tk,H] = act[tk] @ wdT^T (fp32), K=I
__global__ __launch_bounds__(256, 3) void down_kernel(
    const u16* __restrict__ hsh, const u16* __restrict__ sdT,
    const u16* __restrict__ act, const u16* __restrict__ wdT,
    float* __restrict__ sh_out, float* __restrict__ r_out,
    const int* __restrict__ counts, const int* __restrict__ bid)
{
    __shared__ alignas(16) u16 As[128 * 64];
    __shared__ alignas(16) u16 Bs[128 * 64];
    __shared__ int idsL[128];

    int b = blockIdx.x;
    int tid = threadIdx.x;
    bool routed = (b >= 256);
    int e = 0, mblk, nblk, M = T_TOK, K, ldA;
    const u16* A; const u16* BT; float* C;
    if (!routed) {
        // XCD-aware bijective swizzle (256 % 8 == 0)
        int swz = (b & 7) * 32 + (b >> 3);
        mblk = swz & 15; nblk = swz >> 4;
        A = hsh; ldA = SINTER; K = SINTER; BT = sdT; C = sh_out;
    } else {
        int rb = b - 256; e = rb >> 8; int rem = rb & 255;
        mblk = rem & 15; nblk = rem >> 4;
        M = counts[e];
        if (mblk * 128 >= M) return;
        A = act; ldA = MINTER; K = MINTER;
        BT = wdT + (size_t)e * HID * MINTER;
        C = r_out;
    }
    int m0 = mblk * 128, n0 = nblk * 128;

    if (routed) {
        if (tid < 128) {
            int p = m0 + tid; if (p >= M) p = M - 1;
            idsL[tid] = bid[e * T_TOK + p];
        }
        __syncthreads();
    }

    int lane = tid & 63, wid = tid >> 6;
    int rsub = lane >> 3, kseg = (lane & 7) * 8;

    const u16* aG[4]; const u16* bG[4];
    #pragma unroll
    for (int i = 0; i < 4; i++) {
        int rr = wid * 32 + i * 8 + rsub;
        size_t ar = routed ? (size_t)idsL[rr] : (size_t)(m0 + rr);
        aG[i] = A + ar * (size_t)ldA + kseg;
        bG[i] = BT + (size_t)(n0 + rr) * K + kseg;
    }

    f32x4 acc[4][4] = {};
    int wm = (wid & 1) * 64, wn = (wid >> 1) * 64;
    int lrow = lane & 15, lq = lane >> 4;

    for (int k0 = 0; k0 < K; k0 += 64) {
        #pragma unroll
        for (int i = 0; i < 4; i++) {
            gload16(aG[i] + k0, &As[(wid * 32 + i * 8) * 64]);
            gload16(bG[i] + k0, &Bs[(wid * 32 + i * 8) * 64]);
        }
        __syncthreads();
        #pragma unroll
        for (int kc = 0; kc < 64; kc += 32) {
            short8 af[4], bf2[4];
            #pragma unroll
            for (int im = 0; im < 4; im++)
                af[im] = *(const short8*)&As[(wm + im*16 + lrow) * 64 + kc + lq * 8];
            #pragma unroll
            for (int in = 0; in < 4; in++)
                bf2[in] = *(const short8*)&Bs[(wn + in*16 + lrow) * 64 + kc + lq * 8];
            #pragma unroll
            for (int im = 0; im < 4; im++)
                #pragma unroll
                for (int in = 0; in < 4; in++)
                    acc[im][in] = __builtin_amdgcn_mfma_f32_16x16x32_bf16(
                        af[im], bf2[in], acc[im][in], 0, 0, 0);
        }
        __syncthreads();
    }

    #pragma unroll
    for (int im = 0; im < 4; im++) {
        #pragma unroll
        for (int in = 0; in < 4; in++) {
            int ncol = n0 + wn + in*16 + lrow;
            #pragma unroll
            for (int r = 0; r < 4; r++) {
                int mrow = wm + im*16 + lq*4 + r;
                float v = acc[im][in][r];
                if (!routed) {
                    C[(size_t)(m0 + mrow) * HID + ncol] = v;
                } else {
                    if (m0 + mrow < M) {
                        int tk = idsL[mrow];
                        C[(size_t)tk * HID + ncol] = v;
                    }
                }
            }
        }
    }
}

// ---------------- out = shared + routed[2t] + routed[2t+1] ----------------
__global__ __launch_bounds__(256) void final_add_kernel(
    const float* __restrict__ sh, const float* __restrict__ ro,
    float* __restrict__ out, int n4)
{
    int i = blockIdx.x * 256 + threadIdx.x;
    if (i >= n4) return;
    int t  = i >> 9;
    int c4 = i & 511;
    float4 a = ((const float4*)sh)[i];
    float4 b = ((const float4*)ro)[(size_t)(2*t)     * 512 + c4];
    float4 c = ((const float4*)ro)[(size_t)(2*t + 1) * 512 + c4];
    float4 o;
    o.x = a.x + b.x + c.x;
    o.y = a.y + b.y + c.y;
    o.z = a.z + b.z + c.z;
    o.w = a.w + b.w + c.w;
    ((float4*)out)[i] = o;
}

extern "C" void kernel_launch(void* const* d_in, const int* in_sizes, int n_in,
                              void* d_out, int out_size, void* d_ws, size_t ws_size,
                              hipStream_t stream) {
    (void)in_sizes; (void)n_in; (void)out_size; (void)ws_size;
    const float* x  = (const float*)d_in[0];
    const float* rw = (const float*)d_in[1];
    const float* eb = (const float*)d_in[2];
    const float* wu = (const float*)d_in[3];
    const float* wd = (const float*)d_in[4];
    const float* su = (const float*)d_in[5];
    const float* sd = (const float*)d_in[6];
    float* out = (float*)d_out;

    char* p = (char*)d_ws;
    u16*  x_bf = (u16*)p;  p += (size_t)T_TOK * HID * 2;            // 8.4 MB
    u16*  suT  = (u16*)p;  p += (size_t)SINTER * HID * 2;           // 16.8 MB
    u16*  sdT  = (u16*)p;  p += (size_t)HID * SINTER * 2;           // 16.8 MB
    u16*  wuT  = (u16*)p;  p += (size_t)NEXP * MINTER * HID * 2;    // 67.1 MB
    u16*  wdT  = (u16*)p;  p += (size_t)NEXP * HID * MINTER * 2;    // 67.1 MB
    u16*  hsh  = (u16*)p;  p += (size_t)T_TOK * SINTER * 2;         // 16.8 MB
    u16*  act  = (u16*)p;  p += (size_t)T_TOK * 2 * MINTER * 2;     // 8.4 MB
    int*   counts = (int*)p; p += 256;
    int*   bid    = (int*)p; p += (size_t)NEXP * T_TOK * 4;
    float* bw     = (float*)p; p += (size_t)NEXP * T_TOK * 4;
    // aliased (lifetimes disjoint, stream-ordered):
    float* sh_out = (float*)x_bf;   // 16.8 MB over x_bf+suT (dead after up)
    float* r_out  = (float*)wuT;    // 33.6 MB over wuT (dead after up)

    hipMemsetAsync(counts, 0, NEXP * sizeof(int), stream);

    // ONE launch for cvt + all 4 weight transposes + router (independent jobs)
    prep_kernel<<<PREP_BLKS, 256, 0, stream>>>(
        x, su, sd, wu, wd, rw, eb, x_bf, suT, sdT, wuT, wdT, counts, bid, bw);

    // fused up: 512 shared tiles + 16e*8n*16m routed tiles
    up_kernel<<<512 + NEXP * 8 * 16, 256, 0, stream>>>(
        x_bf, suT, wuT, hsh, act, counts, bid, bw);

    // fused down: 256 shared tiles + 16e*16n*16m routed tiles
    down_kernel<<<256 + NEXP * 16 * 16, 256, 0, stream>>>(
        hsh, sdT, act, wdT, sh_out, r_out, counts, bid);

    int n4 = T_TOK * HID / 4;
    final_add_kernel<<<(n4 + 255) / 256, 256, 0, stream>>>(sh_out, r_out, out, n4);
}

// Round 3
// 859.066 us; speedup vs baseline: 1.1719x; 1.0257x over previous
//
#include <hip/hip_runtime.h>
#include <hip/hip_bf16.h>

#define T_TOK 2048
#define HID 2048
#define MINTER 1024
#define SINTER 4096
#define NEXP 16

typedef unsigned short u16;
typedef unsigned int u32;
typedef short short8 __attribute__((ext_vector_type(8)));
typedef float f32x4 __attribute__((ext_vector_type(4)));

__device__ __forceinline__ u16 f2bf(float f) {
    union { float f; unsigned u; } v; v.f = f;
    unsigned u = v.u;
    unsigned r = (u + 0x7FFFu + ((u >> 16) & 1u)) >> 16;
    return (u16)r;
}

// async global->LDS, 16B per lane; LDS dest must be wave-uniform base (+lane*16)
__device__ __forceinline__ void gload16(const void* g, void* s) {
    __builtin_amdgcn_global_load_lds(
        (const __attribute__((address_space(1))) u32*)g,
        (__attribute__((address_space(3))) u32*)s, 16, 0, 0);
}

// ================= fused PREP: cvt + 4 transposes + router in ONE launch =================
#define CVT_BLKS 4096            // (2048*2048/4)/256
#define SU_BLKS  (32 * 64)
#define SD_BLKS  (64 * 32)
#define WU_BLKS  (32 * 16 * 16)
#define WD_BLKS  (16 * 32 * 16)
#define RT_BLKS  T_TOK
#define PREP_BLKS (CVT_BLKS + SU_BLKS + SD_BLKS + WU_BLKS + WD_BLKS + RT_BLKS)

__device__ __forceinline__ void transpose_body(
    const float* __restrict__ in, u16* __restrict__ out,
    int K, int N, int k0, int n0, float (*t)[65])
{
    int tid = threadIdx.x;
    int r = tid >> 4, c4 = (tid & 15) * 4;
    #pragma unroll
    for (int i = 0; i < 4; i++) {
        float4 v = *(const float4*)&in[(size_t)(k0 + r + 16*i) * N + n0 + c4];
        t[r + 16*i][c4]     = v.x;
        t[r + 16*i][c4 + 1] = v.y;
        t[r + 16*i][c4 + 2] = v.z;
        t[r + 16*i][c4 + 3] = v.w;
    }
    __syncthreads();
    #pragma unroll
    for (int i = 0; i < 4; i++) {
        int n = r + 16*i;
        ushort4 o;
        o.x = f2bf(t[c4 + 0][n]);
        o.y = f2bf(t[c4 + 1][n]);
        o.z = f2bf(t[c4 + 2][n]);
        o.w = f2bf(t[c4 + 3][n]);
        *(ushort4*)&out[(size_t)(n0 + n) * K + k0 + c4] = o;
    }
}

__global__ __launch_bounds__(256) void prep_kernel(
    const float* __restrict__ x, const float* __restrict__ su,
    const float* __restrict__ sd, const float* __restrict__ wu,
    const float* __restrict__ wd, const float* __restrict__ rw,
    const float* __restrict__ eb,
    u16* __restrict__ x_bf, u16* __restrict__ suT, u16* __restrict__ sdT,
    u16* __restrict__ wuT, u16* __restrict__ wdT,
    int* __restrict__ counts, int* __restrict__ bid, float* __restrict__ bw)
{
    __shared__ float ts[64][65];
    int b = blockIdx.x;
    int tid = threadIdx.x;

    if (b < CVT_BLKS) {
        int i = b * 256 + tid;
        float4 v = ((const float4*)x)[i];
        ushort4 o;
        o.x = f2bf(v.x); o.y = f2bf(v.y); o.z = f2bf(v.z); o.w = f2bf(v.w);
        ((ushort4*)x_bf)[i] = o;
        return;
    }
    b -= CVT_BLKS;

    if (b < SU_BLKS) {
        transpose_body(su, suT, 2048, 4096, (b & 31) * 64, (b >> 5) * 64, ts);
        return;
    }
    b -= SU_BLKS;

    if (b < SD_BLKS) {
        transpose_body(sd, sdT, 4096, 2048, (b & 63) * 64, (b >> 6) * 64, ts);
        return;
    }
    b -= SD_BLKS;

    if (b < WU_BLKS) {
        int z = b >> 9, r = b & 511;
        size_t zo = (size_t)z * 2048 * 1024;
        transpose_body(wu + zo, wuT + zo, 2048, 1024, (r & 31) * 64, (r >> 5) * 64, ts);
        return;
    }
    b -= WU_BLKS;

    if (b < WD_BLKS) {
        int z = b >> 9, r = b & 511;
        size_t zo = (size_t)z * 1024 * 2048;
        transpose_body(wd + zo, wdT + zo, 1024, 2048, (r & 15) * 64, (r >> 4) * 64, ts);
        return;
    }
    b -= WD_BLKS;

    {
        int t = b;
        int e = tid >> 4, j = tid & 15;
        const float* xp = x + (size_t)t * HID;
        const float* wp = rw + (size_t)e * HID;
        float sum = 0.f;
        #pragma unroll 4
        for (int h = j; h < HID; h += 16) sum += xp[h] * wp[h];
        sum += __shfl_xor(sum, 8);
        sum += __shfl_xor(sum, 4);
        sum += __shfl_xor(sum, 2);
        sum += __shfl_xor(sum, 1);
        float* sc = &ts[0][0];
        if (j == 0) sc[e] = 1.f / (1.f + expf(-sum));
        __syncthreads();
        if (tid == 0) {
            float s[NEXP];
            #pragma unroll
            for (int i = 0; i < NEXP; i++) s[i] = sc[i] + eb[i];
            float gs[4];
            #pragma unroll
            for (int g = 0; g < 4; g++) {
                float a = s[4*g], bq = s[4*g+1], c = s[4*g+2], d = s[4*g+3];
                float hi1 = fmaxf(a,bq), lo1 = fminf(a,bq);
                float hi2 = fmaxf(c,d), lo2 = fminf(c,d);
                float mx = fmaxf(hi1, hi2);
                float se = fmaxf(fminf(hi1, hi2), fmaxf(lo1, lo2));
                gs[g] = mx + se;
            }
            int g0 = 0;
            for (int g = 1; g < 4; g++) if (gs[g] > gs[g0]) g0 = g;
            int g1 = -1;
            for (int g = 0; g < 4; g++) { if (g == g0) continue; if (g1 < 0 || gs[g] > gs[g1]) g1 = g; }
            int e0 = -1, e1 = -1;
            for (int i = 0; i < NEXP; i++) {
                int g = i >> 2;
                if (g != g0 && g != g1) continue;
                if (e0 < 0 || s[i] > s[e0]) e0 = i;
            }
            for (int i = 0; i < NEXP; i++) {
                int g = i >> 2;
                if (g != g0 && g != g1) continue;
                if (i == e0) continue;
                if (e1 < 0 || s[i] > s[e1]) e1 = i;
            }
            float w0 = sc[e0], w1 = sc[e1];
            float inv = 1.f / (w0 + w1 + 1e-20f);
            w0 *= inv; w1 *= inv;
            int p0 = atomicAdd(&counts[e0], 1);
            bid[e0 * T_TOK + p0] = t * 2;
            bw [e0 * T_TOK + p0] = w0;
            int p1 = atomicAdd(&counts[e1], 1);
            bid[e1 * T_TOK + p1] = t * 2 + 1;
            bw [e1 * T_TOK + p1] = w1;
        }
    }
}

// =================== 8-phase 256x256 UP dispatch ===================
// blocks [0,128):  shared-up : hsh[T,S]  = relu2(xbf @ suT^T)       (bf16)
// blocks [128,..): routed-up : act[tk,I] = relu2(xbf[t] @ wuT^T)*w  (bf16)
// 512 thr (8 waves, 2Mx4N), BM=BN=256, BK=64, dbuf LDS 128KB, chunk-XOR swizzle.
__global__ __launch_bounds__(512, 2) void up_kernel(
    const u16* __restrict__ xbf, const u16* __restrict__ suT,
    const u16* __restrict__ wuT, u16* __restrict__ hsh, u16* __restrict__ act,
    const int* __restrict__ counts, const int* __restrict__ bid,
    const float* __restrict__ bw)
{
    __shared__ alignas(16) u16 As[2][256 * 64];
    __shared__ alignas(16) u16 Bs[2][256 * 64];
    __shared__ int   idsL[256];
    __shared__ float wL[256];

    int b = blockIdx.x;
    int tid = threadIdx.x;
    bool routed = (b >= 128);
    int e = 0, mblk, nblk, M = T_TOK;
    const u16* BT;
    if (!routed) {
        int swz = (b & 7) * 16 + (b >> 3);      // 128 = 8 XCD chunks of 16
        mblk = swz >> 4; nblk = swz & 15;       // 8 x 16
        BT = suT;
    } else {
        int rb = b - 128; e = rb >> 5; int rem = rb & 31;
        mblk = rem >> 2; nblk = rem & 3;        // 8 x 4
        M = counts[e];
        if (mblk * 256 >= M) return;
        BT = wuT + (size_t)e * MINTER * HID;
    }
    int m0 = mblk * 256, n0 = nblk * 256;

    if (routed) {
        if (tid < 256) {
            int p = m0 + tid; if (p >= M) p = M - 1;
            idsL[tid] = bid[e * T_TOK + p];
            wL[tid]   = bw [e * T_TOK + p];
        }
        __syncthreads();
    }

    int lane = tid & 63, wid = tid >> 6;
    // ---- staging: wave w covers tile rows [w*32, w*32+32), 4 calls of 8 rows ----
    int srow = lane >> 3;                        // 0..7
    int jch  = ((lane & 7) ^ srow) * 8;          // inverse-swizzled source chunk (elems)
    const u16* aPtr[4]; const u16* bPtr[4];
    #pragma unroll
    for (int c = 0; c < 4; c++) {
        int r = wid * 32 + c * 8 + srow;
        size_t ar = routed ? (size_t)(idsL[r] >> 1) : (size_t)(m0 + r);
        aPtr[c] = xbf + ar * HID + jch;
        bPtr[c] = BT + (size_t)(n0 + r) * HID + jch;
    }

    f32x4 acc[8][4] = {};
    int wm = wid >> 2, wn = wid & 3;             // 2 M-warps x 4 N-warps
    int lrow = lane & 15, lq = lane >> 4;        // lq 0..3
    int rowA = wm * 128 + lrow;                  // + im*16
    int rowB = wn * 64 + lrow;                   // + in*16
    int sA = lrow & 7;
    int co[2];
    co[0] = ((0 * 4 + lq) ^ sA) * 8;             // swizzled chunk offset, kh=0
    co[1] = ((1 * 4 + lq) ^ sA) * 8;             // kh=1

    // prologue: stage tile 0 -> buf 0
    #pragma unroll
    for (int c = 0; c < 4; c++) gload16(aPtr[c], &As[0][(wid * 32 + c * 8) * 64]);
    #pragma unroll
    for (int c = 0; c < 4; c++) gload16(bPtr[c], &Bs[0][(wid * 32 + c * 8) * 64]);
    asm volatile("s_waitcnt vmcnt(0)" ::: "memory");
    __syncthreads();

    const int NT = HID / 64;  // 32
    #pragma unroll 1
    for (int kt = 0; kt < NT; ++kt) {
        int buf = kt & 1;
        // ---- phase 0: stage next tile, read all B-frags + A-frags im 0,1 ----
        if (kt + 1 < NT) {
            int k1 = (kt + 1) * 64;
            #pragma unroll
            for (int c = 0; c < 4; c++) gload16(aPtr[c] + k1, &As[buf ^ 1][(wid * 32 + c * 8) * 64]);
            #pragma unroll
            for (int c = 0; c < 4; c++) gload16(bPtr[c] + k1, &Bs[buf ^ 1][(wid * 32 + c * 8) * 64]);
        }
        short8 bfr[4][2];
        #pragma unroll
        for (int in = 0; in < 4; in++)
            #pragma unroll
            for (int kh = 0; kh < 2; kh++)
                bfr[in][kh] = *(const short8*)&Bs[buf][(rowB + in * 16) * 64 + co[kh]];
        {
            short8 a0[2][2];
            #pragma unroll
            for (int i = 0; i < 2; i++)
                #pragma unroll
                for (int kh = 0; kh < 2; kh++)
                    a0[i][kh] = *(const short8*)&As[buf][(rowA + i * 16) * 64 + co[kh]];
            __builtin_amdgcn_s_barrier();
            __builtin_amdgcn_s_setprio(1);
            #pragma unroll
            for (int i = 0; i < 2; i++)
                #pragma unroll
                for (int in = 0; in < 4; in++)
                    #pragma unroll
                    for (int kh = 0; kh < 2; kh++)
                        acc[i][in] = __builtin_amdgcn_mfma_f32_16x16x32_bf16(
                            a0[i][kh], bfr[in][kh], acc[i][in], 0, 0, 0);
            __builtin_amdgcn_s_setprio(0);
            __builtin_amdgcn_s_barrier();
        }
        // ---- phases 1..3: A-frags im {2p,2p+1} ----
        #pragma unroll
        for (int p = 1; p < 4; p++) {
            short8 ap[2][2];
            #pragma unroll
            for (int i = 0; i < 2; i++)
                #pragma unroll
                for (int kh = 0; kh < 2; kh++)
                    ap[i][kh] = *(const short8*)&As[buf][(rowA + (2 * p + i) * 16) * 64 + co[kh]];
            __builtin_amdgcn_s_barrier();
            __builtin_amdgcn_s_setprio(1);
            #pragma unroll
            for (int i = 0; i < 2; i++)
                #pragma unroll
                for (int in = 0; in < 4; in++)
                    #pragma unroll
                    for (int kh = 0; kh < 2; kh++)
                        acc[2 * p + i][in] = __builtin_amdgcn_mfma_f32_16x16x32_bf16(
                            ap[i][kh], bfr[in][kh], acc[2 * p + i][in], 0, 0, 0);
            __builtin_amdgcn_s_setprio(0);
            if (p < 3) __builtin_amdgcn_s_barrier();
        }
        // ---- K-tile boundary: next tile's loads must have landed ----
        asm volatile("s_waitcnt vmcnt(0)" ::: "memory");
        __builtin_amdgcn_s_barrier();
        __builtin_amdgcn_sched_barrier(0);
    }

    #pragma unroll
    for (int im = 0; im < 8; im++) {
        #pragma unroll
        for (int in = 0; in < 4; in++) {
            int ncol = n0 + wn * 64 + in * 16 + lrow;
            #pragma unroll
            for (int r = 0; r < 4; r++) {
                int mrow = wm * 128 + im * 16 + lq * 4 + r;
                float v = acc[im][in][r];
                float rl = v > 0.f ? v * v : 0.f;
                if (!routed) {
                    hsh[(size_t)(m0 + mrow) * SINTER + ncol] = f2bf(rl);
                } else {
                    if (m0 + mrow < M) {
                        int tk = idsL[mrow];
                        act[(size_t)tk * MINTER + ncol] = f2bf(rl * wL[mrow]);
                    }
                }
            }
        }
    }
}

// =================== 8-phase 256x256 DOWN dispatch ===================
// blocks [0,64):  shared-down: sh_out[T,H] = hsh @ sdT^T   (fp32), K=SINTER
// blocks [64,..): routed-down: r_out[tk,H] = act[tk] @ wdT^T (fp32), K=MINTER
__global__ __launch_bounds__(512, 2) void down_kernel(
    const u16* __restrict__ hsh, const u16* __restrict__ sdT,
    const u16* __restrict__ act, const u16* __restrict__ wdT,
    float* __restrict__ sh_out, float* __restrict__ r_out,
    const int* __restrict__ counts, const int* __restrict__ bid)
{
    __shared__ alignas(16) u16 As[2][256 * 64];
    __shared__ alignas(16) u16 Bs[2][256 * 64];
    __shared__ int idsL[256];

    int b = blockIdx.x;
    int tid = threadIdx.x;
    bool routed = (b >= 64);
    int e = 0, mblk, nblk, M = T_TOK, K, ldA;
    const u16* A; const u16* BT; float* C;
    if (!routed) {
        int swz = (b & 7) * 8 + (b >> 3);       // 64 = 8 XCD chunks of 8
        mblk = swz >> 3; nblk = swz & 7;        // 8 x 8
        A = hsh; ldA = SINTER; K = SINTER; BT = sdT; C = sh_out;
    } else {
        int rb = b - 64; e = rb >> 6; int rem = rb & 63;
        mblk = rem >> 3; nblk = rem & 7;        // 8 x 8
        M = counts[e];
        if (mblk * 256 >= M) return;
        A = act; ldA = MINTER; K = MINTER;
        BT = wdT + (size_t)e * HID * MINTER;
        C = r_out;
    }
    int m0 = mblk * 256, n0 = nblk * 256;

    if (routed) {
        if (tid < 256) {
            int p = m0 + tid; if (p >= M) p = M - 1;
            idsL[tid] = bid[e * T_TOK + p];
        }
        __syncthreads();
    }

    int lane = tid & 63, wid = tid >> 6;
    int srow = lane >> 3;
    int jch  = ((lane & 7) ^ srow) * 8;
    const u16* aPtr[4]; const u16* bPtr[4];
    #pragma unroll
    for (int c = 0; c < 4; c++) {
        int r = wid * 32 + c * 8 + srow;
        size_t ar = routed ? (size_t)idsL[r] : (size_t)(m0 + r);
        aPtr[c] = A + ar * (size_t)ldA + jch;
        bPtr[c] = BT + (size_t)(n0 + r) * K + jch;
    }

    f32x4 acc[8][4] = {};
    int wm = wid >> 2, wn = wid & 3;
    int lrow = lane & 15, lq = lane >> 4;
    int rowA = wm * 128 + lrow;
    int rowB = wn * 64 + lrow;
    int sA = lrow & 7;
    int co[2];
    co[0] = ((0 * 4 + lq) ^ sA) * 8;
    co[1] = ((1 * 4 + lq) ^ sA) * 8;

    #pragma unroll
    for (int c = 0; c < 4; c++) gload16(aPtr[c], &As[0][(wid * 32 + c * 8) * 64]);
    #pragma unroll
    for (int c = 0; c < 4; c++) gload16(bPtr[c], &Bs[0][(wid * 32 + c * 8) * 64]);
    asm volatile("s_waitcnt vmcnt(0)" ::: "memory");
    __syncthreads();

    const int NT = K / 64;  // 64 shared, 16 routed
    #pragma unroll 1
    for (int kt = 0; kt < NT; ++kt) {
        int buf = kt & 1;
        if (kt + 1 < NT) {
            int k1 = (kt + 1) * 64;
            #pragma unroll
            for (int c = 0; c < 4; c++) gload16(aPtr[c] + k1, &As[buf ^ 1][(wid * 32 + c * 8) * 64]);
            #pragma unroll
            for (int c = 0; c < 4; c++) gload16(bPtr[c] + k1, &Bs[buf ^ 1][(wid * 32 + c * 8) * 64]);
        }
        short8 bfr[4][2];
        #pragma unroll
        for (int in = 0; in < 4; in++)
            #pragma unroll
            for (int kh = 0; kh < 2; kh++)
                bfr[in][kh] = *(const short8*)&Bs[buf][(rowB + in * 16) * 64 + co[kh]];
        {
            short8 a0[2][2];
            #pragma unroll
            for (int i = 0; i < 2; i++)
                #pragma unroll
                for (int kh = 0; kh < 2; kh++)
                    a0[i][kh] = *(const short8*)&As[buf][(rowA + i * 16) * 64 + co[kh]];
            __builtin_amdgcn_s_barrier();
            __builtin_amdgcn_s_setprio(1);
            #pragma unroll
            for (int i = 0; i < 2; i++)
                #pragma unroll
                for (int in = 0; in < 4; in++)
                    #pragma unroll
                    for (int kh = 0; kh < 2; kh++)
                        acc[i][in] = __builtin_amdgcn_mfma_f32_16x16x32_bf16(
                            a0[i][kh], bfr[in][kh], acc[i][in], 0, 0, 0);
            __builtin_amdgcn_s_setprio(0);
            __builtin_amdgcn_s_barrier();
        }
        #pragma unroll
        for (int p = 1; p < 4; p++) {
            short8 ap[2][2];
            #pragma unroll
            for (int i = 0; i < 2; i++)
                #pragma unroll
                for (int kh = 0; kh < 2; kh++)
                    ap[i][kh] = *(const short8*)&As[buf][(rowA + (2 * p + i) * 16) * 64 + co[kh]];
            __builtin_amdgcn_s_barrier();
            __builtin_amdgcn_s_setprio(1);
            #pragma unroll
            for (int i = 0; i < 2; i++)
                #pragma unroll
                for (int in = 0; in < 4; in++)
                    #pragma unroll
                    for (int kh = 0; kh < 2; kh++)
                        acc[2 * p + i][in] = __builtin_amdgcn_mfma_f32_16x16x32_bf16(
                            ap[i][kh], bfr[in][kh], acc[2 * p + i][in], 0, 0, 0);
            __builtin_amdgcn_s_setprio(0);
            if (p < 3) __builtin_amdgcn_s_barrier();
        }
        asm volatile("s_waitcnt vmcnt(0)" ::: "memory");
        __builtin_amdgcn_s_barrier();
        __builtin_amdgcn_sched_barrier(0);
    }

    #pragma unroll
    for (int im = 0; im < 8; im++) {
        #pragma unroll
        for (int in = 0; in < 4; in++) {
            int ncol = n0 + wn * 64 + in * 16 + lrow;
            #pragma unroll
            for (int r = 0; r < 4; r++) {
                int mrow = wm * 128 + im * 16 + lq * 4 + r;
                float v = acc[im][in][r];
                if (!routed) {
                    C[(size_t)(m0 + mrow) * HID + ncol] = v;
                } else {
                    if (m0 + mrow < M) {
                        int tk = idsL[mrow];
                        C[(size_t)tk * HID + ncol] = v;
                    }
                }
            }
        }
    }
}

// ---------------- out = shared + routed[2t] + routed[2t+1] ----------------
__global__ __launch_bounds__(256) void final_add_kernel(
    const float* __restrict__ sh, const float* __restrict__ ro,
    float* __restrict__ out, int n4)
{
    int i = blockIdx.x * 256 + threadIdx.x;
    if (i >= n4) return;
    int t  = i >> 9;
    int c4 = i & 511;
    float4 a = ((const float4*)sh)[i];
    float4 b = ((const float4*)ro)[(size_t)(2*t)     * 512 + c4];
    float4 c = ((const float4*)ro)[(size_t)(2*t + 1) * 512 + c4];
    float4 o;
    o.x = a.x + b.x + c.x;
    o.y = a.y + b.y + c.y;
    o.z = a.z + b.z + c.z;
    o.w = a.w + b.w + c.w;
    ((float4*)out)[i] = o;
}

extern "C" void kernel_launch(void* const* d_in, const int* in_sizes, int n_in,
                              void* d_out, int out_size, void* d_ws, size_t ws_size,
                              hipStream_t stream) {
    (void)in_sizes; (void)n_in; (void)out_size; (void)ws_size;
    const float* x  = (const float*)d_in[0];
    const float* rw = (const float*)d_in[1];
    const float* eb = (const float*)d_in[2];
    const float* wu = (const float*)d_in[3];
    const float* wd = (const float*)d_in[4];
    const float* su = (const float*)d_in[5];
    const float* sd = (const float*)d_in[6];
    float* out = (float*)d_out;

    char* p = (char*)d_ws;
    u16*  x_bf = (u16*)p;  p += (size_t)T_TOK * HID * 2;            // 8.4 MB
    u16*  suT  = (u16*)p;  p += (size_t)SINTER * HID * 2;           // 16.8 MB
    u16*  sdT  = (u16*)p;  p += (size_t)HID * SINTER * 2;           // 16.8 MB
    u16*  wuT  = (u16*)p;  p += (size_t)NEXP * MINTER * HID * 2;    // 67.1 MB
    u16*  wdT  = (u16*)p;  p += (size_t)NEXP * HID * MINTER * 2;    // 67.1 MB
    u16*  hsh  = (u16*)p;  p += (size_t)T_TOK * SINTER * 2;         // 16.8 MB
    u16*  act  = (u16*)p;  p += (size_t)T_TOK * 2 * MINTER * 2;     // 8.4 MB
    int*   counts = (int*)p; p += 256;
    int*   bid    = (int*)p; p += (size_t)NEXP * T_TOK * 4;
    float* bw     = (float*)p; p += (size_t)NEXP * T_TOK * 4;
    // aliased (lifetimes disjoint, stream-ordered):
    float* sh_out = (float*)x_bf;   // over x_bf+suT (dead after up)
    float* r_out  = (float*)wuT;    // over wuT (dead after up)

    hipMemsetAsync(counts, 0, NEXP * sizeof(int), stream);

    prep_kernel<<<PREP_BLKS, 256, 0, stream>>>(
        x, su, sd, wu, wd, rw, eb, x_bf, suT, sdT, wuT, wdT, counts, bid, bw);

    // up: 128 shared tiles (8m x 16n) + 16e * (8m x 4n) routed tiles
    up_kernel<<<128 + NEXP * 32, 512, 0, stream>>>(
        x_bf, suT, wuT, hsh, act, counts, bid, bw);

    // down: 64 shared tiles (8m x 8n) + 16e * (8m x 8n) routed tiles
    down_kernel<<<64 + NEXP * 64, 512, 0, stream>>>(
        hsh, sdT, act, wdT, sh_out, r_out, counts, bid);

    int n4 = T_TOK * HID / 4;
    final_add_kernel<<<(n4 + 255) / 256, 256, 0, stream>>>(sh_out, r_out, out, n4);
}

// Round 5
// 625.806 us; speedup vs baseline: 1.6087x; 1.3727x over previous
//
#include <hip/hip_runtime.h>
#include <hip/hip_bf16.h>

#define T_TOK 2048
#define HID 2048
#define MINTER 1024
#define SINTER 4096
#define NEXP 16

typedef unsigned short u16;
typedef unsigned int u32;
typedef short short8 __attribute__((ext_vector_type(8)));
typedef float f32x4 __attribute__((ext_vector_type(4)));

__device__ __forceinline__ u16 f2bf(float f) {
    union { float f; unsigned u; } v; v.f = f;
    unsigned u = v.u;
    unsigned r = (u + 0x7FFFu + ((u >> 16) & 1u)) >> 16;
    return (u16)r;
}

// async global->LDS, 16B per lane; LDS dest must be wave-uniform base (+lane*16)
__device__ __forceinline__ void gload16(const void* g, void* s) {
    __builtin_amdgcn_global_load_lds(
        (const __attribute__((address_space(1))) u32*)g,
        (__attribute__((address_space(3))) u32*)s, 16, 0, 0);
}

// ================= fused PREP: cvt + 4 transposes + router in ONE launch =================
#define CVT_BLKS 4096            // (2048*2048/4)/256
#define SU_BLKS  (32 * 64)
#define SD_BLKS  (64 * 32)
#define WU_BLKS  (32 * 16 * 16)
#define WD_BLKS  (16 * 32 * 16)
#define RT_BLKS  T_TOK
#define PREP_BLKS (CVT_BLKS + SU_BLKS + SD_BLKS + WU_BLKS + WD_BLKS + RT_BLKS)

__device__ __forceinline__ void transpose_body(
    const float* __restrict__ in, u16* __restrict__ out,
    int K, int N, int k0, int n0, float (*t)[65])
{
    int tid = threadIdx.x;
    int r = tid >> 4, c4 = (tid & 15) * 4;
    #pragma unroll
    for (int i = 0; i < 4; i++) {
        float4 v = *(const float4*)&in[(size_t)(k0 + r + 16*i) * N + n0 + c4];
        t[r + 16*i][c4]     = v.x;
        t[r + 16*i][c4 + 1] = v.y;
        t[r + 16*i][c4 + 2] = v.z;
        t[r + 16*i][c4 + 3] = v.w;
    }
    __syncthreads();
    #pragma unroll
    for (int i = 0; i < 4; i++) {
        int n = r + 16*i;
        ushort4 o;
        o.x = f2bf(t[c4 + 0][n]);
        o.y = f2bf(t[c4 + 1][n]);
        o.z = f2bf(t[c4 + 2][n]);
        o.w = f2bf(t[c4 + 3][n]);
        *(ushort4*)&out[(size_t)(n0 + n) * K + k0 + c4] = o;
    }
}

__global__ __launch_bounds__(256) void prep_kernel(
    const float* __restrict__ x, const float* __restrict__ su,
    const float* __restrict__ sd, const float* __restrict__ wu,
    const float* __restrict__ wd, const float* __restrict__ rw,
    const float* __restrict__ eb,
    u16* __restrict__ x_bf, u16* __restrict__ suT, u16* __restrict__ sdT,
    u16* __restrict__ wuT, u16* __restrict__ wdT,
    int* __restrict__ counts, int* __restrict__ bid, float* __restrict__ bw)
{
    __shared__ float ts[64][65];
    int b = blockIdx.x;
    int tid = threadIdx.x;

    if (b < CVT_BLKS) {
        int i = b * 256 + tid;
        float4 v = ((const float4*)x)[i];
        ushort4 o;
        o.x = f2bf(v.x); o.y = f2bf(v.y); o.z = f2bf(v.z); o.w = f2bf(v.w);
        ((ushort4*)x_bf)[i] = o;
        return;
    }
    b -= CVT_BLKS;

    if (b < SU_BLKS) {
        transpose_body(su, suT, 2048, 4096, (b & 31) * 64, (b >> 5) * 64, ts);
        return;
    }
    b -= SU_BLKS;

    if (b < SD_BLKS) {
        transpose_body(sd, sdT, 4096, 2048, (b & 63) * 64, (b >> 6) * 64, ts);
        return;
    }
    b -= SD_BLKS;

    if (b < WU_BLKS) {
        int z = b >> 9, r = b & 511;
        size_t zo = (size_t)z * 2048 * 1024;
        transpose_body(wu + zo, wuT + zo, 2048, 1024, (r & 31) * 64, (r >> 5) * 64, ts);
        return;
    }
    b -= WU_BLKS;

    if (b < WD_BLKS) {
        int z = b >> 9, r = b & 511;
        size_t zo = (size_t)z * 1024 * 2048;
        transpose_body(wd + zo, wdT + zo, 1024, 2048, (r & 15) * 64, (r >> 4) * 64, ts);
        return;
    }
    b -= WD_BLKS;

    {
        int t = b;
        int e = tid >> 4, j = tid & 15;
        const float* xp = x + (size_t)t * HID;
        const float* wp = rw + (size_t)e * HID;
        float sum = 0.f;
        #pragma unroll 4
        for (int h = j; h < HID; h += 16) sum += xp[h] * wp[h];
        sum += __shfl_xor(sum, 8);
        sum += __shfl_xor(sum, 4);
        sum += __shfl_xor(sum, 2);
        sum += __shfl_xor(sum, 1);
        float* sc = &ts[0][0];
        if (j == 0) sc[e] = 1.f / (1.f + expf(-sum));
        __syncthreads();
        if (tid == 0) {
            float s[NEXP];
            #pragma unroll
            for (int i = 0; i < NEXP; i++) s[i] = sc[i] + eb[i];
            float gs[4];
            #pragma unroll
            for (int g = 0; g < 4; g++) {
                float a = s[4*g], bq = s[4*g+1], c = s[4*g+2], d = s[4*g+3];
                float hi1 = fmaxf(a,bq), lo1 = fminf(a,bq);
                float hi2 = fmaxf(c,d), lo2 = fminf(c,d);
                float mx = fmaxf(hi1, hi2);
                float se = fmaxf(fminf(hi1, hi2), fmaxf(lo1, lo2));
                gs[g] = mx + se;
            }
            int g0 = 0;
            for (int g = 1; g < 4; g++) if (gs[g] > gs[g0]) g0 = g;
            int g1 = -1;
            for (int g = 0; g < 4; g++) { if (g == g0) continue; if (g1 < 0 || gs[g] > gs[g1]) g1 = g; }
            int e0 = -1, e1 = -1;
            for (int i = 0; i < NEXP; i++) {
                int g = i >> 2;
                if (g != g0 && g != g1) continue;
                if (e0 < 0 || s[i] > s[e0]) e0 = i;
            }
            for (int i = 0; i < NEXP; i++) {
                int g = i >> 2;
                if (g != g0 && g != g1) continue;
                if (i == e0) continue;
                if (e1 < 0 || s[i] > s[e1]) e1 = i;
            }
            float w0 = sc[e0], w1 = sc[e1];
            float inv = 1.f / (w0 + w1 + 1e-20f);
            w0 *= inv; w1 *= inv;
            int p0 = atomicAdd(&counts[e0], 1);
            bid[e0 * T_TOK + p0] = t * 2;
            bw [e0 * T_TOK + p0] = w0;
            int p1 = atomicAdd(&counts[e1], 1);
            bid[e1 * T_TOK + p1] = t * 2 + 1;
            bw [e1 * T_TOK + p1] = w1;
        }
    }
}

// compact routed-tile mapping: rb -> (e, mblk, nblk) over LIVE tiles only.
// RNB = N-tiles per (expert, m-tile). Returns e=-1 if rb beyond live work.
__device__ __forceinline__ void map_routed(
    const int* __restrict__ counts, int rb, int RNB_LOG, int& e, int& mblk, int& nblk, int& M)
{
    e = -1; mblk = 0; nblk = 0; M = 0;
    int acc = 0;
    #pragma unroll 1
    for (int i = 0; i < NEXP; i++) {
        int c = counts[i];
        int nt = ((c + 255) >> 8) << RNB_LOG;
        if (e < 0 && rb >= acc && rb < acc + nt) {
            e = i; M = c;
            int lo = rb - acc;
            mblk = lo >> RNB_LOG;
            nblk = lo & ((1 << RNB_LOG) - 1);
        }
        acc += nt;
    }
}

// =================== 8-phase 256x256 UP dispatch ===================
// blocks [0,128):   shared-up : hsh[T,S]  = relu2(xbf @ suT^T)       (bf16)
// blocks [128,256): routed-up : act[tk,I] = relu2(xbf[t] @ wuT^T)*w  (bf16)  [compact]
__global__ __launch_bounds__(512, 2) void up_kernel(
    const u16* __restrict__ xbf, const u16* __restrict__ suT,
    const u16* __restrict__ wuT, u16* __restrict__ hsh, u16* __restrict__ act,
    const int* __restrict__ counts, const int* __restrict__ bid,
    const float* __restrict__ bw)
{
    __shared__ alignas(16) u16 As[2][256 * 64];
    __shared__ alignas(16) u16 Bs[2][256 * 64];
    __shared__ int   idsL[256];
    __shared__ float wL[256];

    int b = blockIdx.x;
    int tid = threadIdx.x;
    bool routed = (b >= 128);
    int e = 0, mblk, nblk, M = T_TOK;
    const u16* BT;
    if (!routed) {
        int swz = (b & 7) * 16 + (b >> 3);      // 128 = 8 XCD chunks of 16
        mblk = swz >> 4; nblk = swz & 15;       // 8 x 16
        BT = suT;
    } else {
        map_routed(counts, b - 128, 2, e, mblk, nblk, M);   // RNB=4 (1024/256)
        if (e < 0) return;
        BT = wuT + (size_t)e * MINTER * HID;
    }
    int m0 = mblk * 256, n0 = nblk * 256;

    if (routed) {
        if (tid < 256) {
            int p = m0 + tid; if (p >= M) p = M - 1;
            idsL[tid] = bid[e * T_TOK + p];
            wL[tid]   = bw [e * T_TOK + p];
        }
        __syncthreads();
    }

    int lane = tid & 63, wid = tid >> 6;
    int srow = lane >> 3;                        // 0..7
    int jch  = ((lane & 7) ^ srow) * 8;          // inverse-swizzled source chunk (elems)
    const u16* aPtr[4]; const u16* bPtr[4];
    #pragma unroll
    for (int c = 0; c < 4; c++) {
        int r = wid * 32 + c * 8 + srow;
        size_t ar = routed ? (size_t)(idsL[r] >> 1) : (size_t)(m0 + r);
        aPtr[c] = xbf + ar * HID + jch;
        bPtr[c] = BT + (size_t)(n0 + r) * HID + jch;
    }

    f32x4 acc[8][4] = {};
    int wm = wid >> 2, wn = wid & 3;             // 2 M-warps x 4 N-warps
    int lrow = lane & 15, lq = lane >> 4;        // lq 0..3
    int rowA = wm * 128 + lrow;
    int rowB = wn * 64 + lrow;
    int sA = lrow & 7;
    int co[2];
    co[0] = ((0 * 4 + lq) ^ sA) * 8;
    co[1] = ((1 * 4 + lq) ^ sA) * 8;

    #pragma unroll
    for (int c = 0; c < 4; c++) gload16(aPtr[c], &As[0][(wid * 32 + c * 8) * 64]);
    #pragma unroll
    for (int c = 0; c < 4; c++) gload16(bPtr[c], &Bs[0][(wid * 32 + c * 8) * 64]);
    asm volatile("s_waitcnt vmcnt(0)" ::: "memory");
    __syncthreads();

    const int NT = HID / 64;  // 32
    #pragma unroll 1
    for (int kt = 0; kt < NT; ++kt) {
        int buf = kt & 1;
        if (kt + 1 < NT) {
            int k1 = (kt + 1) * 64;
            #pragma unroll
            for (int c = 0; c < 4; c++) gload16(aPtr[c] + k1, &As[buf ^ 1][(wid * 32 + c * 8) * 64]);
            #pragma unroll
            for (int c = 0; c < 4; c++) gload16(bPtr[c] + k1, &Bs[buf ^ 1][(wid * 32 + c * 8) * 64]);
        }
        short8 bfr[4][2];
        #pragma unroll
        for (int in = 0; in < 4; in++)
            #pragma unroll
            for (int kh = 0; kh < 2; kh++)
                bfr[in][kh] = *(const short8*)&Bs[buf][(rowB + in * 16) * 64 + co[kh]];
        {
            short8 a0[2][2];
            #pragma unroll
            for (int i = 0; i < 2; i++)
                #pragma unroll
                for (int kh = 0; kh < 2; kh++)
                    a0[i][kh] = *(const short8*)&As[buf][(rowA + i * 16) * 64 + co[kh]];
            __builtin_amdgcn_s_barrier();
            __builtin_amdgcn_s_setprio(1);
            #pragma unroll
            for (int i = 0; i < 2; i++)
                #pragma unroll
                for (int in = 0; in < 4; in++)
                    #pragma unroll
                    for (int kh = 0; kh < 2; kh++)
                        acc[i][in] = __builtin_amdgcn_mfma_f32_16x16x32_bf16(
                            a0[i][kh], bfr[in][kh], acc[i][in], 0, 0, 0);
            __builtin_amdgcn_s_setprio(0);
            __builtin_amdgcn_s_barrier();
        }
        #pragma unroll
        for (int p = 1; p < 4; p++) {
            short8 ap[2][2];
            #pragma unroll
            for (int i = 0; i < 2; i++)
                #pragma unroll
                for (int kh = 0; kh < 2; kh++)
                    ap[i][kh] = *(const short8*)&As[buf][(rowA + (2 * p + i) * 16) * 64 + co[kh]];
            __builtin_amdgcn_s_barrier();
            __builtin_amdgcn_s_setprio(1);
            #pragma unroll
            for (int i = 0; i < 2; i++)
                #pragma unroll
                for (int in = 0; in < 4; in++)
                    #pragma unroll
                    for (int kh = 0; kh < 2; kh++)
                        acc[2 * p + i][in] = __builtin_amdgcn_mfma_f32_16x16x32_bf16(
                            ap[i][kh], bfr[in][kh], acc[2 * p + i][in], 0, 0, 0);
            __builtin_amdgcn_s_setprio(0);
            if (p < 3) __builtin_amdgcn_s_barrier();
        }
        asm volatile("s_waitcnt vmcnt(0)" ::: "memory");
        __builtin_amdgcn_s_barrier();
        __builtin_amdgcn_sched_barrier(0);
    }

    #pragma unroll
    for (int im = 0; im < 8; im++) {
        #pragma unroll
        for (int in = 0; in < 4; in++) {
            int ncol = n0 + wn * 64 + in * 16 + lrow;
            #pragma unroll
            for (int r = 0; r < 4; r++) {
                int mrow = wm * 128 + im * 16 + lq * 4 + r;
                float v = acc[im][in][r];
                float rl = v > 0.f ? v * v : 0.f;
                if (!routed) {
                    hsh[(size_t)(m0 + mrow) * SINTER + ncol] = f2bf(rl);
                } else {
                    if (m0 + mrow < M) {
                        int tk = idsL[mrow];
                        act[(size_t)tk * MINTER + ncol] = f2bf(rl * wL[mrow]);
                    }
                }
            }
        }
    }
}

// =================== 8-phase 256x256 DOWN dispatch ===================
// blocks [0,128):   shared-down split-K: partial[T,H] = hsh[:,kh] @ sdT[:,kh]^T (fp32)
// blocks [128,384): routed-down: r_out[tk,H] = act[tk] @ wdT^T (fp32)  [compact]
__global__ __launch_bounds__(512, 2) void down_kernel(
    const u16* __restrict__ hsh, const u16* __restrict__ sdT,
    const u16* __restrict__ act, const u16* __restrict__ wdT,
    float* __restrict__ sh_out0, float* __restrict__ sh_out1,
    float* __restrict__ r_out,
    const int* __restrict__ counts, const int* __restrict__ bid)
{
    __shared__ alignas(16) u16 As[2][256 * 64];
    __shared__ alignas(16) u16 Bs[2][256 * 64];
    __shared__ int idsL[256];

    int b = blockIdx.x;
    int tid = threadIdx.x;
    bool routed = (b >= 128);
    int e = 0, mblk, nblk, M = T_TOK, K, ldA, koff = 0, NT;
    const u16* A; const u16* BT; float* C;
    if (!routed) {
        int sb = b >> 1, kh = b & 1;            // 64 tiles x 2 K-halves
        int swz = (sb & 7) * 8 + (sb >> 3);     // XCD chunks
        mblk = swz >> 3; nblk = swz & 7;        // 8 x 8
        A = hsh; ldA = SINTER; K = SINTER; BT = sdT;
        koff = kh * 2048; NT = 2048 / 64;       // 32 K-tiles per half
        C = kh ? sh_out1 : sh_out0;
    } else {
        map_routed(counts, b - 128, 3, e, mblk, nblk, M);   // RNB=8 (2048/256)
        if (e < 0) return;
        A = act; ldA = MINTER; K = MINTER;
        BT = wdT + (size_t)e * HID * MINTER;
        koff = 0; NT = MINTER / 64;             // 16
        C = r_out;
    }
    int m0 = mblk * 256, n0 = nblk * 256;

    if (routed) {
        if (tid < 256) {
            int p = m0 + tid; if (p >= M) p = M - 1;
            idsL[tid] = bid[e * T_TOK + p];
        }
        __syncthreads();
    }

    int lane = tid & 63, wid = tid >> 6;
    int srow = lane >> 3;
    int jch  = ((lane & 7) ^ srow) * 8;
    const u16* aPtr[4]; const u16* bPtr[4];
    #pragma unroll
    for (int c = 0; c < 4; c++) {
        int r = wid * 32 + c * 8 + srow;
        size_t ar = routed ? (size_t)idsL[r] : (size_t)(m0 + r);
        aPtr[c] = A + ar * (size_t)ldA + koff + jch;
        bPtr[c] = BT + (size_t)(n0 + r) * K + koff + jch;
    }

    f32x4 acc[8][4] = {};
    int wm = wid >> 2, wn = wid & 3;
    int lrow = lane & 15, lq = lane >> 4;
    int rowA = wm * 128 + lrow;
    int rowB = wn * 64 + lrow;
    int sA = lrow & 7;
    int co[2];
    co[0] = ((0 * 4 + lq) ^ sA) * 8;
    co[1] = ((1 * 4 + lq) ^ sA) * 8;

    #pragma unroll
    for (int c = 0; c < 4; c++) gload16(aPtr[c], &As[0][(wid * 32 + c * 8) * 64]);
    #pragma unroll
    for (int c = 0; c < 4; c++) gload16(bPtr[c], &Bs[0][(wid * 32 + c * 8) * 64]);
    asm volatile("s_waitcnt vmcnt(0)" ::: "memory");
    __syncthreads();

    #pragma unroll 1
    for (int kt = 0; kt < NT; ++kt) {
        int buf = kt & 1;
        if (kt + 1 < NT) {
            int k1 = (kt + 1) * 64;
            #pragma unroll
            for (int c = 0; c < 4; c++) gload16(aPtr[c] + k1, &As[buf ^ 1][(wid * 32 + c * 8) * 64]);
            #pragma unroll
            for (int c = 0; c < 4; c++) gload16(bPtr[c] + k1, &Bs[buf ^ 1][(wid * 32 + c * 8) * 64]);
        }
        short8 bfr[4][2];
        #pragma unroll
        for (int in = 0; in < 4; in++)
            #pragma unroll
            for (int kh = 0; kh < 2; kh++)
                bfr[in][kh] = *(const short8*)&Bs[buf][(rowB + in * 16) * 64 + co[kh]];
        {
            short8 a0[2][2];
            #pragma unroll
            for (int i = 0; i < 2; i++)
                #pragma unroll
                for (int kh = 0; kh < 2; kh++)
                    a0[i][kh] = *(const short8*)&As[buf][(rowA + i * 16) * 64 + co[kh]];
            __builtin_amdgcn_s_barrier();
            __builtin_amdgcn_s_setprio(1);
            #pragma unroll
            for (int i = 0; i < 2; i++)
                #pragma unroll
                for (int in = 0; in < 4; in++)
                    #pragma unroll
                    for (int kh = 0; kh < 2; kh++)
                        acc[i][in] = __builtin_amdgcn_mfma_f32_16x16x32_bf16(
                            a0[i][kh], bfr[in][kh], acc[i][in], 0, 0, 0);
            __builtin_amdgcn_s_setprio(0);
            __builtin_amdgcn_s_barrier();
        }
        #pragma unroll
        for (int p = 1; p < 4; p++) {
            short8 ap[2][2];
            #pragma unroll
            for (int i = 0; i < 2; i++)
                #pragma unroll
                for (int kh = 0; kh < 2; kh++)
                    ap[i][kh] = *(const short8*)&As[buf][(rowA + (2 * p + i) * 16) * 64 + co[kh]];
            __builtin_amdgcn_s_barrier();
            __builtin_amdgcn_s_setprio(1);
            #pragma unroll
            for (int i = 0; i < 2; i++)
                #pragma unroll
                for (int in = 0; in < 4; in++)
                    #pragma unroll
                    for (int kh = 0; kh < 2; kh++)
                        acc[2 * p + i][in] = __builtin_amdgcn_mfma_f32_16x16x32_bf16(
                            ap[i][kh], bfr[in][kh], acc[2 * p + i][in], 0, 0, 0);
            __builtin_amdgcn_s_setprio(0);
            if (p < 3) __builtin_amdgcn_s_barrier();
        }
        asm volatile("s_waitcnt vmcnt(0)" ::: "memory");
        __builtin_amdgcn_s_barrier();
        __builtin_amdgcn_sched_barrier(0);
    }

    #pragma unroll
    for (int im = 0; im < 8; im++) {
        #pragma unroll
        for (int in = 0; in < 4; in++) {
            int ncol = n0 + wn * 64 + in * 16 + lrow;
            #pragma unroll
            for (int r = 0; r < 4; r++) {
                int mrow = wm * 128 + im * 16 + lq * 4 + r;
                float v = acc[im][in][r];
                if (!routed) {
                    C[(size_t)(m0 + mrow) * HID + ncol] = v;
                } else {
                    if (m0 + mrow < M) {
                        int tk = idsL[mrow];
                        C[(size_t)tk * HID + ncol] = v;
                    }
                }
            }
        }
    }
}

// ---------------- out = sh0 + sh1 + routed[2t] + routed[2t+1] ----------------
__global__ __launch_bounds__(256) void final_add_kernel(
    const float* __restrict__ sh0, const float* __restrict__ sh1,
    const float* __restrict__ ro, float* __restrict__ out, int n4)
{
    int i = blockIdx.x * 256 + threadIdx.x;
    if (i >= n4) return;
    int t  = i >> 9;
    int c4 = i & 511;
    float4 a = ((const float4*)sh0)[i];
    float4 a2 = ((const float4*)sh1)[i];
    float4 b = ((const float4*)ro)[(size_t)(2*t)     * 512 + c4];
    float4 c = ((const float4*)ro)[(size_t)(2*t + 1) * 512 + c4];
    float4 o;
    o.x = a.x + a2.x + b.x + c.x;
    o.y = a.y + a2.y + b.y + c.y;
    o.z = a.z + a2.z + b.z + c.z;
    o.w = a.w + a2.w + b.w + c.w;
    ((float4*)out)[i] = o;
}

extern "C" void kernel_launch(void* const* d_in, const int* in_sizes, int n_in,
                              void* d_out, int out_size, void* d_ws, size_t ws_size,
                              hipStream_t stream) {
    (void)in_sizes; (void)n_in; (void)out_size; (void)ws_size;
    const float* x  = (const float*)d_in[0];
    const float* rw = (const float*)d_in[1];
    const float* eb = (const float*)d_in[2];
    const float* wu = (const float*)d_in[3];
    const float* wd = (const float*)d_in[4];
    const float* su = (const float*)d_in[5];
    const float* sd = (const float*)d_in[6];
    float* out = (float*)d_out;

    char* p = (char*)d_ws;
    u16*  x_bf = (u16*)p;  p += (size_t)T_TOK * HID * 2;            // 8.4 MB
    u16*  suT  = (u16*)p;  p += (size_t)SINTER * HID * 2;           // 16.8 MB
    u16*  sdT  = (u16*)p;  p += (size_t)HID * SINTER * 2;           // 16.8 MB
    u16*  wuT  = (u16*)p;  p += (size_t)NEXP * MINTER * HID * 2;    // 67.1 MB
    u16*  wdT  = (u16*)p;  p += (size_t)NEXP * HID * MINTER * 2;    // 67.1 MB
    u16*  hsh  = (u16*)p;  p += (size_t)T_TOK * SINTER * 2;         // 16.8 MB
    u16*  act  = (u16*)p;  p += (size_t)T_TOK * 2 * MINTER * 2;     // 8.4 MB
    int*   counts = (int*)p; p += 256;
    int*   bid    = (int*)p; p += (size_t)NEXP * T_TOK * 4;
    float* bw     = (float*)p; p += (size_t)NEXP * T_TOK * 4;
    // aliased (lifetimes disjoint, stream-ordered); all dead after up:
    //   r_out   = wuT bytes [0, 33.6MB)         (T_TOK*2*HID floats)
    //   sh_out1 = wuT bytes [33.6MB, 50.4MB)    (T_TOK*HID floats)  -- FIXED offset
    float* sh_out0 = (float*)x_bf;                          // 16.8 MB over x_bf+suT
    float* r_out   = (float*)wuT;                           // 33.6 MB over wuT
    float* sh_out1 = (float*)wuT + (size_t)T_TOK * 2 * HID; // float-elem offset = 33.6 MB

    hipMemsetAsync(counts, 0, NEXP * sizeof(int), stream);

    prep_kernel<<<PREP_BLKS, 256, 0, stream>>>(
        x, su, sd, wu, wd, rw, eb, x_bf, suT, sdT, wuT, wdT, counts, bid, bw);

    // up: 128 shared tiles + <=128 compact routed tiles
    up_kernel<<<128 + 128, 512, 0, stream>>>(
        x_bf, suT, wuT, hsh, act, counts, bid, bw);

    // down: 128 split-K shared tiles + <=256 compact routed tiles
    down_kernel<<<128 + 256, 512, 0, stream>>>(
        hsh, sdT, act, wdT, sh_out0, sh_out1, r_out, counts, bid);

    int n4 = T_TOK * HID / 4;
    final_add_kernel<<<(n4 + 255) / 256, 256, 0, stream>>>(sh_out0, sh_out1, r_out, out, n4);
}